// Round 1
// baseline (363.342 us; speedup 1.0000x reference)
//
#include <hip/hip_runtime.h>

#define DN 64
#define DE 32
#define DO 64

// ---------------------------------------------------------------------------
// Kernel A: per-node projections through the edge-MLP weight:
//   Ps[n] = node[n] @ W_e[0:64]      (src part)
//   Pd[n] = node[n] @ W_e[96:160]    (dst part)
// One wave per node (grid-stride). Lane j owns output column j and caches
// W columns in VGPRs; x row is wave-uniform (scalar loads / L1 broadcast).
// ---------------------------------------------------------------------------
__global__ void __launch_bounds__(256) node_pre_kernel(
    const float* __restrict__ node, const float* __restrict__ W_e,
    float* __restrict__ Ps, float* __restrict__ Pd, int n_nodes)
{
    const int lane = threadIdx.x & 63;
    const int wid  = __builtin_amdgcn_readfirstlane((int)(threadIdx.x >> 6));
    const int wpb  = blockDim.x >> 6;
    const int gw   = blockIdx.x * wpb + wid;
    const int nw   = gridDim.x * wpb;

    float Ws[64], Wd[64];
#pragma unroll
    for (int k = 0; k < 64; ++k) {
        Ws[k] = W_e[(size_t)k * DO + lane];          // rows 0..63
        Wd[k] = W_e[(size_t)(96 + k) * DO + lane];   // rows 96..159
    }

    for (int n = gw; n < n_nodes; n += nw) {
        const float* __restrict__ x = node + (size_t)n * DN;
        float as = 0.f, ad = 0.f;
#pragma unroll
        for (int k = 0; k < 64; ++k) {
            const float xk = x[k];
            as = fmaf(xk, Ws[k], as);
            ad = fmaf(xk, Wd[k], ad);
        }
        Ps[(size_t)n * DO + lane] = as;
        Pd[(size_t)n * DO + lane] = ad;
    }
}

// ---------------------------------------------------------------------------
// Kernel B: per-edge message + atomic mean-aggregation.
//   m = relu(Ps[src] + edge @ W_e[64:96] + Pd[dst] + b_e)
//   msum[dst] += m (atomic), deg[dst] += 1 (atomic, lane 0)
// One wave per edge (grid-stride). Lane j owns column j; W_mid column in
// 32 VGPRs; edge row is wave-uniform.
// ---------------------------------------------------------------------------
__global__ void __launch_bounds__(256) edge_kernel(
    const float* __restrict__ edge, const int* __restrict__ src,
    const int* __restrict__ dst,
    const float* __restrict__ W_e, const float* __restrict__ b_e,
    const float* __restrict__ Ps, const float* __restrict__ Pd,
    float* __restrict__ msum, float* __restrict__ deg, int n_edges)
{
    const int lane = threadIdx.x & 63;
    const int wid  = __builtin_amdgcn_readfirstlane((int)(threadIdx.x >> 6));
    const int wpb  = blockDim.x >> 6;
    const int gw   = blockIdx.x * wpb + wid;
    const int nw   = gridDim.x * wpb;

    float Wm[32];
#pragma unroll
    for (int k = 0; k < 32; ++k)
        Wm[k] = W_e[(size_t)(64 + k) * DO + lane];   // rows 64..95
    const float bj = b_e[lane];

    for (int e = gw; e < n_edges; e += nw) {
        const int s = src[e];
        const int d = dst[e];
        const float* __restrict__ er = edge + (size_t)e * DE;
        float acc = bj + Ps[(size_t)s * DO + lane] + Pd[(size_t)d * DO + lane];
#pragma unroll
        for (int k = 0; k < 32; ++k)
            acc = fmaf(er[k], Wm[k], acc);
        acc = fmaxf(acc, 0.f);
        atomicAdd(&msum[(size_t)d * DO + lane], acc);
        if (lane == 0) atomicAdd(&deg[d], 1.f);
    }
}

// ---------------------------------------------------------------------------
// Kernel C: node update:
//   neigh = deg>0 ? msum/deg : 0
//   out = relu(neigh @ W_v[0:64] + node @ W_v[64:128] + b_v)
// Note neigh@Wt = (msum@Wt)/deg (deg is a scalar per node), so divide once.
// ---------------------------------------------------------------------------
__global__ void __launch_bounds__(256) node_out_kernel(
    const float* __restrict__ node, const float* __restrict__ msum,
    const float* __restrict__ deg,
    const float* __restrict__ W_v, const float* __restrict__ b_v,
    float* __restrict__ out, int n_nodes)
{
    const int lane = threadIdx.x & 63;
    const int wid  = __builtin_amdgcn_readfirstlane((int)(threadIdx.x >> 6));
    const int wpb  = blockDim.x >> 6;
    const int gw   = blockIdx.x * wpb + wid;
    const int nw   = gridDim.x * wpb;

    float Wt[64], Wb[64];
#pragma unroll
    for (int k = 0; k < 64; ++k) {
        Wt[k] = W_v[(size_t)k * DO + lane];          // rows 0..63 (neigh)
        Wb[k] = W_v[(size_t)(64 + k) * DO + lane];   // rows 64..127 (node)
    }
    const float bj = b_v[lane];

    for (int n = gw; n < n_nodes; n += nw) {
        const float* __restrict__ ms = msum + (size_t)n * DO;
        const float* __restrict__ x  = node + (size_t)n * DN;
        const float dg = deg[n];
        float an = 0.f, ax = 0.f;
#pragma unroll
        for (int k = 0; k < 64; ++k) {
            an = fmaf(ms[k], Wt[k], an);
            ax = fmaf(x[k],  Wb[k], ax);
        }
        float acc = bj + ax + (dg > 0.f ? an / dg : 0.f);
        out[(size_t)n * DO + lane] = fmaxf(acc, 0.f);
    }
}

extern "C" void kernel_launch(void* const* d_in, const int* in_sizes, int n_in,
                              void* d_out, int out_size, void* d_ws, size_t ws_size,
                              hipStream_t stream)
{
    const float* node = (const float*)d_in[0];
    const float* edge = (const float*)d_in[1];
    const int*   src  = (const int*)d_in[2];
    const int*   dst  = (const int*)d_in[3];
    const float* W_e  = (const float*)d_in[4];
    const float* b_e  = (const float*)d_in[5];
    const float* W_v  = (const float*)d_in[6];
    const float* b_v  = (const float*)d_in[7];
    float* out = (float*)d_out;

    const int n_nodes = in_sizes[0] / DN;
    const int n_edges = in_sizes[2];

    // Workspace layout (floats): Ps | Pd | msum | deg
    float* Ps   = (float*)d_ws;
    float* Pd   = Ps   + (size_t)n_nodes * DO;
    float* msum = Pd   + (size_t)n_nodes * DO;
    float* deg  = msum + (size_t)n_nodes * DO;

    // Zero the accumulators every call (graph-replay safe).
    hipMemsetAsync(msum, 0, ((size_t)n_nodes * DO + n_nodes) * sizeof(float), stream);

    node_pre_kernel<<<512, 256, 0, stream>>>(node, W_e, Ps, Pd, n_nodes);
    edge_kernel<<<2048, 256, 0, stream>>>(edge, src, dst, W_e, b_e, Ps, Pd,
                                          msum, deg, n_edges);
    node_out_kernel<<<512, 256, 0, stream>>>(node, msum, deg, W_v, b_v,
                                             out, n_nodes);
}